// Round 2
// baseline (1248.763 us; speedup 1.0000x reference)
//
#include <hip/hip_runtime.h>
#include <stdint.h>

// VQ-VAE codebook argmin, f32 in / f32 out.
// R7: revert R6's manual pipeline (regressed +180us: raw-barrier/vmcnt convoy
// exposed LLC latency every step). Back to the R5-proven sync structure
// (__syncthreads pairs, compiler-managed waits, zero inline asm), keeping two
// R6 elements that are HW-verified: (a) fragment-major conflict-free LDS
// layout via pre-swizzled global_load_lds SOURCE (linear LDS dest), and
// (b) nothing else. New lever: BK=64 — stage A+B for 64 k-elems (32KB) per
// barrier pair, 32 MFMA/wave per drain instead of 16. Halves the number of
// LLC-latency drains (512 -> 256) at identical LDS footprint (32KB).
// Packed top-2 per (row,slice) + exact numpy-f32 re-rank of 16 candidates
// (R4-proven anchor) unchanged. bf16 scratch lives in d_out's z_q region.

#define B_ROWS 32768
#define DIM    512
#define KCODES 8192
#define SUPERS 2
#define TILES  32   // per super: 32 tiles * 128 = 4096 codes

typedef short bhalf8_t __attribute__((ext_vector_type(8)));
typedef float f32x4_t  __attribute__((ext_vector_type(4)));

__device__ __forceinline__ float b2f(unsigned short u) {
    return __uint_as_float(((unsigned int)u) << 16);
}
__device__ __forceinline__ unsigned short f2b(float f) {  // RNE
    unsigned int x = __float_as_uint(f);
    return (unsigned short)((x + 0x7FFFu + ((x >> 16) & 1u)) >> 16);
}
__device__ __forceinline__ void gl_lds16(const void* g, void* l) {
    __builtin_amdgcn_global_load_lds(
        (const __attribute__((address_space(1))) unsigned int*)g,
        (__attribute__((address_space(3))) unsigned int*)l, 16, 0, 0);
}

// ---------- K0: f32 -> bf16 (hi only) ----------
__global__ __launch_bounds__(256) void k_split(const float4* __restrict__ src,
                                               ushort4* __restrict__ dst, int n4) {
    int i = blockIdx.x * 256 + threadIdx.x;
    int stride = gridDim.x * 256;
    for (; i < n4; i += stride) {
        float4 v = src[i];
        ushort4 h;
        h.x = f2b(v.x); h.y = f2b(v.y); h.z = f2b(v.z); h.w = f2b(v.w);
        dst[i] = h;
    }
}

// ---------- K1: numpy-pairwise-emulated row sum of squares (R4-proven) ----------
__global__ __launch_bounds__(256) void k_pairsq(const float* __restrict__ X,
                                                float* __restrict__ out, int nrows) {
    int wid = threadIdx.x >> 6, lane = threadIdx.x & 63;
    int r = blockIdx.x * 4 + wid;
    if (r >= nrows) return;
    int b = lane >> 3, j = lane & 7;
    float acc = 0.f;
    if (b < 4) {
        const float* x = X + (size_t)r * DIM + b * 128 + j;
        float v = x[0];
        acc = __fmul_rn(v, v);
        for (int i = 1; i < 16; i++) {
            float w = x[8 * i];
            acc = __fadd_rn(acc, __fmul_rn(w, w));
        }
    }
    float t = __fadd_rn(acc, __shfl_xor(acc, 1));
    t = __fadd_rn(t, __shfl_xor(t, 2));
    t = __fadd_rn(t, __shfl_xor(t, 4));
    float u = __fadd_rn(t, __shfl_xor(t, 8));
    u = __fadd_rn(u, __shfl_xor(u, 16));
    if (lane == 0) out[r] = u;
}

// ---------- K2: bf16 MFMA GEMM + packed top-2/(row,slice) -> top-8/super ----------
// LDS map (32KB total, same footprint as R5):
//   [0,16K)   = A tile, 128 rows x 64 k  (two 8KB fragment-major 32-k slices)
//   [16K,32K) = B tile, 128 rows x 64 k  (same)
// Fragment-major (per 8KB slice): element (row, kseg) at byte
//   (row>>4)*1024 + kseg*256 + (row&15)*16
// so a wave's fragment read  base + f*1024 + lane*16  is one contiguous 1024B
// chunk (conflict-free ds_read_b128; HW-verified in R6). global_load_lds dest
// stays LINEAR (lane-contiguous); the permutation is applied to the per-lane
// GLOBAL source address instead (both-sides-or-neither rule).
__device__ __forceinline__ void compute_slice(const unsigned char* ba,
                                              const unsigned char* bb,
                                              int lane, f32x4_t acc[4][4]) {
    bhalf8_t af[4], bf[4];
#pragma unroll
    for (int f = 0; f < 4; f++) {
        af[f] = *(const bhalf8_t*)(ba + f * 1024 + lane * 16);
        bf[f] = *(const bhalf8_t*)(bb + f * 1024 + lane * 16);
    }
#pragma unroll
    for (int fm = 0; fm < 4; fm++)
#pragma unroll
        for (int fn = 0; fn < 4; fn++)
            acc[fm][fn] = __builtin_amdgcn_mfma_f32_16x16x32_bf16(af[fm], bf[fn], acc[fm][fn], 0, 0, 0);
}

__global__ __launch_bounds__(256) void k_argmin(const unsigned short* __restrict__ Zh,
                                                const unsigned short* __restrict__ Wh,
                                                const float* __restrict__ ww,
                                                float2* __restrict__ part) {
    __shared__ alignas(16) unsigned char smem[32768];
    const int tid = threadIdx.x;
    const int lane = tid & 63, w = tid >> 6;
    const int wm = w >> 1, wn = w & 1;
    const int lane15 = lane & 15, q = lane >> 4;
    const int b = blockIdx.x;
    const int super = b & 1;
    const int rb = (b >> 1) * 128;

    // staging decode, constant per thread (HW-verified mapping from R6):
    // slot s in an 8KB slice holds (row = (s>>6)*16 + (s&15), kseg = (s>>4)&3);
    // this thread owns slots tid (rows 0..63) and tid+256 (rows 64..127).
    const int rowO0 = ((tid >> 6) << 4) | (tid & 15);
    const int kO0   = ((tid >> 4) & 3) << 3;            // bf16 k-offset in 32-k slice
    const int dst0  = tid * 16;                         // bytes; +4096 for upper rows

    uint32_t p1[4][4], p2[4][4];
#pragma unroll
    for (int i = 0; i < 4; i++)
#pragma unroll
        for (int jj = 0; jj < 4; jj++) { p1[i][jj] = 0xFFFFFFFFu; p2[i][jj] = 0xFFFFFFFFu; }

    for (int tl = 0; tl < TILES; ++tl) {
        const int nt = super * 4096 + tl * 128;
        f32x4_t acc[4][4];
#pragma unroll
        for (int i = 0; i < 4; i++)
#pragma unroll
            for (int jj = 0; jj < 4; jj++) acc[i][jj] = (f32x4_t){0.f, 0.f, 0.f, 0.f};

        for (int kb = 0; kb < DIM; kb += 64) {
            __syncthreads();  // prior LDS readers done
#pragma unroll
            for (int sl = 0; sl < 2; sl++) {
                unsigned char* sA = smem + sl * 8192;
                unsigned char* sB = smem + 16384 + sl * 8192;
                const int kg = kb + sl * 32 + kO0;
                gl_lds16(Zh + (size_t)(rb + rowO0) * DIM + kg,      sA + dst0);
                gl_lds16(Zh + (size_t)(rb + rowO0 + 64) * DIM + kg, sA + 4096 + dst0);
                gl_lds16(Wh + (size_t)(nt + rowO0) * DIM + kg,      sB + dst0);
                gl_lds16(Wh + (size_t)(nt + rowO0 + 64) * DIM + kg, sB + 4096 + dst0);
            }
            __syncthreads();  // vmcnt(0) drain before use (compiler-managed)

#pragma unroll
            for (int sl = 0; sl < 2; sl++)
                compute_slice(smem + sl * 8192 + wm * 4096,
                              smem + 16384 + sl * 8192 + wn * 4096, lane, acc);
        }

        // epilogue: s' = (ww[n]+0.5) - 2*dot  (positive => float bits monotonic);
        // pack: high-25 bits of score | 7-bit candidate id (tl*4+fn). Strict '<'
        // insert in ascending (tl,fn) => smaller n wins ties within a slice.
        float cb[4];
#pragma unroll
        for (int fn = 0; fn < 4; fn++)
            cb[fn] = ww[nt + wn * 64 + fn * 16 + lane15] + 0.5f;
#pragma unroll
        for (int fm = 0; fm < 4; fm++)
#pragma unroll
            for (int r = 0; r < 4; r++)
#pragma unroll
                for (int fn = 0; fn < 4; fn++) {
                    float sv = fmaf(-2.0f, acc[fm][fn][r], cb[fn]);
                    uint32_t pk = (__float_as_uint(sv) & 0xFFFFFF80u) | (uint32_t)(tl * 4 + fn);
                    if (pk < p1[fm][r]) { p2[fm][r] = p1[fm][r]; p1[fm][r] = pk; }
                    else if (pk < p2[fm][r]) { p2[fm][r] = pk; }
                }
    }

    // per-row top-8 of 64 packed keys via LDS
    __syncthreads();
    uint32_t* keys = (uint32_t*)smem;   // [128 rows][32 slices][2 slots]
#pragma unroll
    for (int fm = 0; fm < 4; fm++)
#pragma unroll
        for (int r = 0; r < 4; r++) {
            int row = wm * 64 + fm * 16 + q * 4 + r;   // C/D row = (lane>>4)*4 + reg
            int slice = wn * 16 + lane15;
            keys[(row * 32 + slice) * 2 + 0] = p1[fm][r];
            keys[(row * 32 + slice) * 2 + 1] = p2[fm][r];
        }
    __syncthreads();
    if (tid < 128) {
        int row = tid;
        int rglob = rb + row;
        for (int s = 0; s < 8; s++) {
            uint32_t bk = 0xFFFFFFFFu; int be = 0;
            for (int e = 0; e < 64; e++) {
                uint32_t k = keys[row * 64 + e];
                if (k < bk) { bk = k; be = e; }
            }
            int slice = be >> 1;
            int id = (int)(bk & 127u);
            int n = super * 4096 + (id >> 2) * 128 + (slice >> 4) * 64 + (id & 3) * 16 + (slice & 15);
            part[((size_t)rglob * SUPERS + super) * 8 + s] =
                make_float2(__uint_as_float(bk), __int_as_float(n));
            keys[row * 64 + be] = 0xFFFFFFFFu;  // consume
        }
    }
}

// ---------- K3: exact numpy-f32 re-rank of 16 candidates, outputs (R4-proven) ----------
__global__ __launch_bounds__(256) void k_exact(const float* __restrict__ Zf,
                                               const float* __restrict__ Wf,
                                               const float2* __restrict__ part,
                                               const float* __restrict__ zz,
                                               const float* __restrict__ ww,
                                               float* __restrict__ outf,
                                               float* __restrict__ lossp) {
    __shared__ float wsum[4];
    int wid = threadIdx.x >> 6, lane = threadIdx.x & 63;
    int r = blockIdx.x * 4 + wid;
    int c = lane >> 2, j = lane & 3;   // candidate 0..15, SSE lane 0..3

    float2 P = part[((size_t)r * SUPERS + (c >> 3)) * 8 + (c & 7)];
    int n = __float_as_int(P.y);
    n = min(max(n, 0), KCODES - 1);

    // numpy einsum baseline-SIMD: 4 stride-4 f32 accumulators (mul+add, no FMA)
    const float* zp = Zf + (size_t)r * DIM + j;
    const float* wp = Wf + (size_t)n * DIM + j;
    float acc = 0.f;
    for (int i = 0; i < 128; i++)
        acc = __fadd_rn(acc, __fmul_rn(zp[4 * i], wp[4 * i]));
    float t = __fadd_rn(acc, __shfl_xor(acc, 1));
    t = __fadd_rn(t, __shfl_xor(t, 2));
    float dot = __shfl(t, c * 4);

    float t1 = __fadd_rn(zz[r], ww[n]);
    float t2 = __fmul_rn(2.0f, dot);
    float d2 = __fadd_rn(t1, -t2);

    float bd = (j == 0) ? d2 : 3.4e38f;
    int   bn = (j == 0) ? n  : 0x7FFFFFFF;
#pragma unroll
    for (int off = 32; off; off >>= 1) {
        float od = __shfl_xor(bd, off);
        int   on = __shfl_xor(bn, off);
        if (od < bd || (od == bd && on < bn)) { bd = od; bn = on; }
    }
    int idx = bn;

    float4 wa = *(const float4*)(Wf + (size_t)idx * DIM + lane * 8);
    float4 wb = *(const float4*)(Wf + (size_t)idx * DIM + lane * 8 + 4);
    float4 za = *(const float4*)(Zf + (size_t)r   * DIM + lane * 8);
    float4 zb = *(const float4*)(Zf + (size_t)r   * DIM + lane * 8 + 4);
    *(float4*)(outf + (size_t)r * DIM + lane * 8)     = wa;
    *(float4*)(outf + (size_t)r * DIM + lane * 8 + 4) = wb;
    float d0 = za.x - wa.x, d1 = za.y - wa.y, dd2 = za.z - wa.z, d3 = za.w - wa.w;
    float d4 = zb.x - wb.x, d5 = zb.y - wb.y, d6 = zb.z - wb.z, d7 = zb.w - wb.w;
    float ls = d0*d0 + d1*d1 + dd2*dd2 + d3*d3 + d4*d4 + d5*d5 + d6*d6 + d7*d7;
#pragma unroll
    for (int off = 32; off; off >>= 1) ls += __shfl_xor(ls, off);
    if (lane == 0) {
        outf[(size_t)B_ROWS * DIM + r] = (float)idx;
        wsum[wid] = ls;
    }
    __syncthreads();
    if (threadIdx.x == 0) lossp[blockIdx.x] = wsum[0] + wsum[1] + wsum[2] + wsum[3];
}

// ---------- K4: loss reduction ----------
__global__ __launch_bounds__(256) void k_loss(const float* __restrict__ lossp,
                                              float* __restrict__ outf) {
    __shared__ float sm[256];
    float a = 0.f;
    for (int i = threadIdx.x; i < 8192; i += 256) a += lossp[i];
    sm[threadIdx.x] = a;
    __syncthreads();
    for (int s = 128; s; s >>= 1) {
        if (threadIdx.x < s) sm[threadIdx.x] += sm[threadIdx.x + s];
        __syncthreads();
    }
    if (threadIdx.x == 0)
        outf[(size_t)B_ROWS * DIM + B_ROWS] = 1.25f * sm[0] / 16777216.0f;
}

extern "C" void kernel_launch(void* const* d_in, const int* in_sizes, int n_in,
                              void* d_out, int out_size, void* d_ws, size_t ws_size,
                              hipStream_t stream) {
    (void)in_sizes; (void)n_in; (void)out_size; (void)ws_size;
    const float* Zf = (const float*)d_in[0];   // [32768, 512] f32
    const float* Wf = (const float*)d_in[1];   // [8192, 512]  f32
    float* outf = (float*)d_out;               // f32: z_q | indices | loss

    // bf16 scratch inside d_out's z_q region (64 MB): Zh 32MB @0 | Wh 8MB @32MB.
    // k_exact overwrites it with the final z_q (k_argmin has completed by then).
    unsigned short* Zh = (unsigned short*)d_out;
    unsigned short* Wh = (unsigned short*)((char*)d_out + (32ull << 20));

    // ws (4.39 MB, proven): ww 32KB @0 | zz 128KB @32K | lossp 32KB @160K | part 4MB @192K
    float*  ww    = (float*)d_ws;
    float*  zz    = (float*)((char*)d_ws + 32768);
    float*  lossp = (float*)((char*)d_ws + 163840);
    float2* partp = (float2*)((char*)d_ws + 196608);

    k_split<<<1024, 256, 0, stream>>>((const float4*)Zf, (ushort4*)Zh, B_ROWS * DIM / 4);
    k_split<<<512,  256, 0, stream>>>((const float4*)Wf, (ushort4*)Wh, KCODES * DIM / 4);
    k_pairsq<<<KCODES / 4, 256, 0, stream>>>(Wf, ww, KCODES);
    k_pairsq<<<B_ROWS / 4, 256, 0, stream>>>(Zf, zz, B_ROWS);
    k_argmin<<<(B_ROWS / 128) * SUPERS, 256, 0, stream>>>(Zh, Wh, ww, partp);
    k_exact<<<B_ROWS / 4, 256, 0, stream>>>(Zf, Wf, partp, zz, ww, outf, lossp);
    k_loss<<<1, 256, 0, stream>>>(lossp, outf);
}

// Round 3
// 874.755 us; speedup vs baseline: 1.4276x; 1.4276x over previous
//
#include <hip/hip_runtime.h>
#include <stdint.h>

// VQ-VAE codebook argmin, f32 in / f32 out.
// R8: occupancy round. R6/R7 both regressed because VGPR went 128->136 and
// crossed the wave-budget cliff (m69): 2 resident blocks/CU -> 1, killing the
// inter-block latency hiding R5 relied on. Fix: (1) exact R5 sync structure
// (BK=32, __syncthreads pair, compiler-managed waits), (2) HW-verified
// fragment-major conflict-free LDS layout kept, (3) __launch_bounds__(256,4)
// pins VGPR<=128 (4 waves/SIMD), (4) SUPERS=4 (2048 codes/block, TILES=16)
// -> 1024 blocks = 4 blocks/CU (LDS 4x32KB=128KB fits). XCD bonus: super=b&3
// with XCD=b&7 gives each XCD one 2MB W-slice, fully L2-resident.
// k_exact numerics unchanged (still exactly 16 candidates): k_argmin now
// keeps top-4 per super x 4 supers (was top-8 x 2). part stays 4MB.

#define B_ROWS 32768
#define DIM    512
#define KCODES 8192
#define SUPERS 4
#define TILES  16   // per super: 16 tiles * 128 = 2048 codes

typedef short bhalf8_t __attribute__((ext_vector_type(8)));
typedef float f32x4_t  __attribute__((ext_vector_type(4)));

__device__ __forceinline__ float b2f(unsigned short u) {
    return __uint_as_float(((unsigned int)u) << 16);
}
__device__ __forceinline__ unsigned short f2b(float f) {  // RNE
    unsigned int x = __float_as_uint(f);
    return (unsigned short)((x + 0x7FFFu + ((x >> 16) & 1u)) >> 16);
}
__device__ __forceinline__ void gl_lds16(const void* g, void* l) {
    __builtin_amdgcn_global_load_lds(
        (const __attribute__((address_space(1))) unsigned int*)g,
        (__attribute__((address_space(3))) unsigned int*)l, 16, 0, 0);
}

// ---------- K0: f32 -> bf16 (hi only) ----------
__global__ __launch_bounds__(256) void k_split(const float4* __restrict__ src,
                                               ushort4* __restrict__ dst, int n4) {
    int i = blockIdx.x * 256 + threadIdx.x;
    int stride = gridDim.x * 256;
    for (; i < n4; i += stride) {
        float4 v = src[i];
        ushort4 h;
        h.x = f2b(v.x); h.y = f2b(v.y); h.z = f2b(v.z); h.w = f2b(v.w);
        dst[i] = h;
    }
}

// ---------- K1: numpy-pairwise-emulated row sum of squares (R4-proven) ----------
__global__ __launch_bounds__(256) void k_pairsq(const float* __restrict__ X,
                                                float* __restrict__ out, int nrows) {
    int wid = threadIdx.x >> 6, lane = threadIdx.x & 63;
    int r = blockIdx.x * 4 + wid;
    if (r >= nrows) return;
    int b = lane >> 3, j = lane & 7;
    float acc = 0.f;
    if (b < 4) {
        const float* x = X + (size_t)r * DIM + b * 128 + j;
        float v = x[0];
        acc = __fmul_rn(v, v);
        for (int i = 1; i < 16; i++) {
            float w = x[8 * i];
            acc = __fadd_rn(acc, __fmul_rn(w, w));
        }
    }
    float t = __fadd_rn(acc, __shfl_xor(acc, 1));
    t = __fadd_rn(t, __shfl_xor(t, 2));
    t = __fadd_rn(t, __shfl_xor(t, 4));
    float u = __fadd_rn(t, __shfl_xor(t, 8));
    u = __fadd_rn(u, __shfl_xor(u, 16));
    if (lane == 0) out[r] = u;
}

// ---------- K2: bf16 MFMA GEMM + packed top-2/(row,slice) -> top-4/super ----------
// LDS per step (16KB live): A slice [0,8K), B slice [8K,16K). smem=32KB for
// the final keys reduce. Fragment-major slice layout (HW-verified R6/R7):
// element (row, kseg) of a 128x32 bf16 slice at byte
//   (row>>4)*1024 + kseg*256 + (row&15)*16
// so a wave's fragment read base + f*1024 + lane*16 is one contiguous 1024B
// chunk (conflict-free ds_read_b128). global_load_lds dest stays LINEAR
// (lane-contiguous); the permutation is applied to the per-lane GLOBAL
// source address instead (both-sides-or-neither rule).
__device__ __forceinline__ void compute_slice(const unsigned char* ba,
                                              const unsigned char* bb,
                                              int lane, f32x4_t acc[4][4]) {
    bhalf8_t af[4], bf[4];
#pragma unroll
    for (int f = 0; f < 4; f++) {
        af[f] = *(const bhalf8_t*)(ba + f * 1024 + lane * 16);
        bf[f] = *(const bhalf8_t*)(bb + f * 1024 + lane * 16);
    }
#pragma unroll
    for (int fm = 0; fm < 4; fm++)
#pragma unroll
        for (int fn = 0; fn < 4; fn++)
            acc[fm][fn] = __builtin_amdgcn_mfma_f32_16x16x32_bf16(af[fm], bf[fn], acc[fm][fn], 0, 0, 0);
}

__global__ __launch_bounds__(256, 4) void k_argmin(const unsigned short* __restrict__ Zh,
                                                   const unsigned short* __restrict__ Wh,
                                                   const float* __restrict__ ww,
                                                   float2* __restrict__ part) {
    __shared__ alignas(16) unsigned char smem[32768];
    const int tid = threadIdx.x;
    const int lane = tid & 63, w = tid >> 6;
    const int wm = w >> 1, wn = w & 1;
    const int lane15 = lane & 15, q = lane >> 4;
    const int b = blockIdx.x;
    const int super = b & 3;          // XCD = b&7 -> each XCD sees ONE super (W slice 2MB, L2-resident)
    const int rb = (b >> 2) * 128;

    // staging decode, constant per thread (HW-verified): slot s of an 8KB
    // slice holds (row = (s>>6)*16 + (s&15), kseg = (s>>4)&3); thread tid
    // owns slot tid (rows 0..63) and slot tid+256 (rows 64..127, dst+4096).
    const int rowO0 = ((tid >> 6) << 4) | (tid & 15);
    const int kO0   = ((tid >> 4) & 3) << 3;            // bf16 k-offset in 32-k slice
    const int dst0  = tid * 16;

    uint32_t p1[4][4], p2[4][4];
#pragma unroll
    for (int i = 0; i < 4; i++)
#pragma unroll
        for (int jj = 0; jj < 4; jj++) { p1[i][jj] = 0xFFFFFFFFu; p2[i][jj] = 0xFFFFFFFFu; }

    for (int tl = 0; tl < TILES; ++tl) {
        const int nt = super * 2048 + tl * 128;
        f32x4_t acc[4][4];
#pragma unroll
        for (int i = 0; i < 4; i++)
#pragma unroll
            for (int jj = 0; jj < 4; jj++) acc[i][jj] = (f32x4_t){0.f, 0.f, 0.f, 0.f};

        for (int kb = 0; kb < DIM; kb += 32) {
            __syncthreads();  // prior LDS readers done
            const int kg = kb + kO0;
            gl_lds16(Zh + (size_t)(rb + rowO0) * DIM + kg,      smem + dst0);
            gl_lds16(Zh + (size_t)(rb + rowO0 + 64) * DIM + kg, smem + 4096 + dst0);
            gl_lds16(Wh + (size_t)(nt + rowO0) * DIM + kg,      smem + 8192 + dst0);
            gl_lds16(Wh + (size_t)(nt + rowO0 + 64) * DIM + kg, smem + 8192 + 4096 + dst0);
            __syncthreads();  // vmcnt(0) drain before use (compiler-managed)

            compute_slice(smem + wm * 4096, smem + 8192 + wn * 4096, lane, acc);
        }

        // epilogue: s' = (ww[n]+0.5) - 2*dot  (positive => float bits monotonic);
        // pack: high-25 bits of score | 7-bit candidate id (tl*4+fn, <64).
        // Strict '<' insert in ascending (tl,fn) => smaller n wins slice ties.
        float cb[4];
#pragma unroll
        for (int fn = 0; fn < 4; fn++)
            cb[fn] = ww[nt + wn * 64 + fn * 16 + lane15] + 0.5f;
#pragma unroll
        for (int fm = 0; fm < 4; fm++)
#pragma unroll
            for (int r = 0; r < 4; r++)
#pragma unroll
                for (int fn = 0; fn < 4; fn++) {
                    float sv = fmaf(-2.0f, acc[fm][fn][r], cb[fn]);
                    uint32_t pk = (__float_as_uint(sv) & 0xFFFFFF80u) | (uint32_t)(tl * 4 + fn);
                    if (pk < p1[fm][r]) { p2[fm][r] = p1[fm][r]; p1[fm][r] = pk; }
                    else if (pk < p2[fm][r]) { p2[fm][r] = pk; }
                }
    }

    // per-row top-4 of 64 packed keys via LDS
    __syncthreads();
    uint32_t* keys = (uint32_t*)smem;   // [128 rows][32 slices][2 slots]
#pragma unroll
    for (int fm = 0; fm < 4; fm++)
#pragma unroll
        for (int r = 0; r < 4; r++) {
            int row = wm * 64 + fm * 16 + q * 4 + r;   // C/D row = (lane>>4)*4 + reg
            int slice = wn * 16 + lane15;
            keys[(row * 32 + slice) * 2 + 0] = p1[fm][r];
            keys[(row * 32 + slice) * 2 + 1] = p2[fm][r];
        }
    __syncthreads();
    if (tid < 128) {
        int row = tid;
        int rglob = rb + row;
        for (int s = 0; s < 4; s++) {
            uint32_t bk = 0xFFFFFFFFu; int be = 0;
            for (int e = 0; e < 64; e++) {
                uint32_t k = keys[row * 64 + e];
                if (k < bk) { bk = k; be = e; }
            }
            int slice = be >> 1;
            int id = (int)(bk & 127u);
            int n = super * 2048 + (id >> 2) * 128 + (slice >> 4) * 64 + (id & 3) * 16 + (slice & 15);
            part[((size_t)rglob * SUPERS + super) * 4 + s] =
                make_float2(__uint_as_float(bk), __int_as_float(n));
            keys[row * 64 + be] = 0xFFFFFFFFu;  // consume
        }
    }
}

// ---------- K3: exact numpy-f32 re-rank of 16 candidates, outputs (R4-proven) ----------
__global__ __launch_bounds__(256) void k_exact(const float* __restrict__ Zf,
                                               const float* __restrict__ Wf,
                                               const float2* __restrict__ part,
                                               const float* __restrict__ zz,
                                               const float* __restrict__ ww,
                                               float* __restrict__ outf,
                                               float* __restrict__ lossp) {
    __shared__ float wsum[4];
    int wid = threadIdx.x >> 6, lane = threadIdx.x & 63;
    int r = blockIdx.x * 4 + wid;
    int c = lane >> 2, j = lane & 3;   // candidate 0..15, SSE lane 0..3

    // candidates: 4 supers x top-4
    float2 P = part[((size_t)r * SUPERS + (c >> 2)) * 4 + (c & 3)];
    int n = __float_as_int(P.y);
    n = min(max(n, 0), KCODES - 1);

    // numpy einsum baseline-SIMD: 4 stride-4 f32 accumulators (mul+add, no FMA)
    const float* zp = Zf + (size_t)r * DIM + j;
    const float* wp = Wf + (size_t)n * DIM + j;
    float acc = 0.f;
    for (int i = 0; i < 128; i++)
        acc = __fadd_rn(acc, __fmul_rn(zp[4 * i], wp[4 * i]));
    float t = __fadd_rn(acc, __shfl_xor(acc, 1));
    t = __fadd_rn(t, __shfl_xor(t, 2));
    float dot = __shfl(t, c * 4);

    float t1 = __fadd_rn(zz[r], ww[n]);
    float t2 = __fmul_rn(2.0f, dot);
    float d2 = __fadd_rn(t1, -t2);

    float bd = (j == 0) ? d2 : 3.4e38f;
    int   bn = (j == 0) ? n  : 0x7FFFFFFF;
#pragma unroll
    for (int off = 32; off; off >>= 1) {
        float od = __shfl_xor(bd, off);
        int   on = __shfl_xor(bn, off);
        if (od < bd || (od == bd && on < bn)) { bd = od; bn = on; }
    }
    int idx = bn;

    float4 wa = *(const float4*)(Wf + (size_t)idx * DIM + lane * 8);
    float4 wb = *(const float4*)(Wf + (size_t)idx * DIM + lane * 8 + 4);
    float4 za = *(const float4*)(Zf + (size_t)r   * DIM + lane * 8);
    float4 zb = *(const float4*)(Zf + (size_t)r   * DIM + lane * 8 + 4);
    *(float4*)(outf + (size_t)r * DIM + lane * 8)     = wa;
    *(float4*)(outf + (size_t)r * DIM + lane * 8 + 4) = wb;
    float d0 = za.x - wa.x, d1 = za.y - wa.y, dd2 = za.z - wa.z, d3 = za.w - wa.w;
    float d4 = zb.x - wb.x, d5 = zb.y - wb.y, d6 = zb.z - wb.z, d7 = zb.w - wb.w;
    float ls = d0*d0 + d1*d1 + dd2*dd2 + d3*d3 + d4*d4 + d5*d5 + d6*d6 + d7*d7;
#pragma unroll
    for (int off = 32; off; off >>= 1) ls += __shfl_xor(ls, off);
    if (lane == 0) {
        outf[(size_t)B_ROWS * DIM + r] = (float)idx;
        wsum[wid] = ls;
    }
    __syncthreads();
    if (threadIdx.x == 0) lossp[blockIdx.x] = wsum[0] + wsum[1] + wsum[2] + wsum[3];
}

// ---------- K4: loss reduction ----------
__global__ __launch_bounds__(256) void k_loss(const float* __restrict__ lossp,
                                              float* __restrict__ outf) {
    __shared__ float sm[256];
    float a = 0.f;
    for (int i = threadIdx.x; i < 8192; i += 256) a += lossp[i];
    sm[threadIdx.x] = a;
    __syncthreads();
    for (int s = 128; s; s >>= 1) {
        if (threadIdx.x < s) sm[threadIdx.x] += sm[threadIdx.x + s];
        __syncthreads();
    }
    if (threadIdx.x == 0)
        outf[(size_t)B_ROWS * DIM + B_ROWS] = 1.25f * sm[0] / 16777216.0f;
}

extern "C" void kernel_launch(void* const* d_in, const int* in_sizes, int n_in,
                              void* d_out, int out_size, void* d_ws, size_t ws_size,
                              hipStream_t stream) {
    (void)in_sizes; (void)n_in; (void)out_size; (void)ws_size;
    const float* Zf = (const float*)d_in[0];   // [32768, 512] f32
    const float* Wf = (const float*)d_in[1];   // [8192, 512]  f32
    float* outf = (float*)d_out;               // f32: z_q | indices | loss

    // bf16 scratch inside d_out's z_q region (64 MB): Zh 32MB @0 | Wh 8MB @32MB.
    // k_exact overwrites it with the final z_q (k_argmin has completed by then).
    unsigned short* Zh = (unsigned short*)d_out;
    unsigned short* Wh = (unsigned short*)((char*)d_out + (32ull << 20));

    // ws (4.39 MB, proven): ww 32KB @0 | zz 128KB @32K | lossp 32KB @160K | part 4MB @192K
    // part layout: [row][super(4)][4 entries] float2 = 4MB (same size as before).
    float*  ww    = (float*)d_ws;
    float*  zz    = (float*)((char*)d_ws + 32768);
    float*  lossp = (float*)((char*)d_ws + 163840);
    float2* partp = (float2*)((char*)d_ws + 196608);

    k_split<<<1024, 256, 0, stream>>>((const float4*)Zf, (ushort4*)Zh, B_ROWS * DIM / 4);
    k_split<<<512,  256, 0, stream>>>((const float4*)Wf, (ushort4*)Wh, KCODES * DIM / 4);
    k_pairsq<<<KCODES / 4, 256, 0, stream>>>(Wf, ww, KCODES);
    k_pairsq<<<B_ROWS / 4, 256, 0, stream>>>(Zf, zz, B_ROWS);
    k_argmin<<<(B_ROWS / 128) * SUPERS, 256, 0, stream>>>(Zh, Wh, ww, partp);
    k_exact<<<B_ROWS / 4, 256, 0, stream>>>(Zf, Wf, partp, zz, ww, outf, lossp);
    k_loss<<<1, 256, 0, stream>>>(lossp, outf);
}